// Round 16
// baseline (214.207 us; speedup 1.0000x reference)
//
#include <hip/hip_runtime.h>
#include <cstdint>

constexpr int NV = 32000;   // vocab / N
constexpr int NE = 256;     // embed dim
constexpr int NH = 512;     // hidden / K
constexpr int NB = 8;       // batch
constexpr int NS = 16;      // seq len
constexpr int NT = 20;      // time steps
constexpr float TH1 = 0.8f;
constexpr float TH2 = 1.0f;

typedef _Float16 f16x8 __attribute__((ext_vector_type(8)));
typedef float f32x4 __attribute__((ext_vector_type(4)));

__device__ inline float clip01(float v) { return fminf(fmaxf(v, 0.f), 1.f); }

// LDS-write drain + barrier (vmcnt left in flight: A prefetch crosses barriers)
__device__ inline void bar_lds() {
  asm volatile("s_waitcnt lgkmcnt(0)" ::: "memory");
  __builtin_amdgcn_s_barrier();
  __builtin_amdgcn_sched_barrier(0);
}

// ---------------- K_front: embed+fc1 dots (regs) -> leaky recurrence -> A2F spikes --------
// Grid 16 x 256.  Block = (batch b = blk>>1, h-half).  cur1 never touches memory.
// A2F layout (f16): frag(mt,kfi,rb) at ((mt*16+kfi)*4+rb)*512; elem at lr*32 + (h&31)
// where row=(gs&7)*8+b, rb=row>>4, lr=row&15.  Stores: 64 consecutive h -> 2x64B runs.
__global__ __launch_bounds__(256) void k_front(
    const int* __restrict__ x, const float* __restrict__ embed,
    const float* __restrict__ W1, const float* __restrict__ b1,
    const float* __restrict__ pbeta1,
    _Float16* __restrict__ A2F, float* __restrict__ mem1_out) {
  __shared__ float emb[16][256];
  const int tid = threadIdx.x;
  const int blk = blockIdx.x;
  const int b   = blk >> 1;
  const int h   = ((blk & 1) << 8) + tid;

  for (int s = 0; s < 16; ++s) {
    const int row = x[b * 16 + s];
    emb[s][tid] = embed[(size_t)row * NE + tid];
  }
  __syncthreads();

  // ---- 16 dots of length 256 (ILP-16, emb via LDS broadcast) ----
  float c[16];
#pragma unroll
  for (int s = 0; s < 16; ++s) c[s] = 0.f;
  const float* w = W1 + (size_t)h * NE;
  for (int e4 = 0; e4 < 64; ++e4) {
    const float4 wv = *(const float4*)(w + e4 * 4);
#pragma unroll
    for (int s = 0; s < 16; ++s) {
      const float4 ev = *(const float4*)&emb[s][e4 * 4];
      c[s] = fmaf(wv.w, ev.w, fmaf(wv.z, ev.z, fmaf(wv.y, ev.y, fmaf(wv.x, ev.x, c[s]))));
    }
  }
  const float bias = b1[h];
#pragma unroll
  for (int s = 0; s < 16; ++s) c[s] = c[s] + bias;

  // ---- leaky recurrence, spikes -> A2F ----
  const float bc = clip01(pbeta1[0]);
  const int kfi = h >> 5;
  const int k31 = h & 31;
  float mem = 0.f;
  const _Float16 one  = (_Float16)1.0f;
  const _Float16 zero = (_Float16)0.0f;
#pragma unroll
  for (int s = 0; s < 16; ++s) {
    const float cs = c[s];
    for (int t = 0; t < NT; ++t) {
      float rst = (mem > TH1) ? TH1 : 0.f;
      mem = __fsub_rn(__fadd_rn(__fmul_rn(bc, mem), cs), rst);   // np order
      bool spk = mem > TH1;
      const int gs  = s * NT + t;
      const int row = (gs & 7) * 8 + b;
      size_t addr = (((size_t)(gs >> 3) * 16 + kfi) * 4 + (row >> 4)) * 512
                  + (row & 15) * 32 + k31;
      A2F[addr] = spk ? one : zero;
    }
  }
  mem1_out[b * NH + h] = mem;
}

// ---------------- Fused: A-from-L2 fp16 GEMM (n=128 strip) + overlapped recurrence --------
// Grid 250 = 1 block/CU.  Block = 1024 thr = 16 waves: (kq 2) x (wm 2) x (wn 4).
// B (W2 slice, fp16, n=32 x K=256) in registers.  A frags straight from L2-resident A2F.
// Cl DOUBLE-buffered -> ONE barrier per mt; recurrence(mt-1) overlaps GEMM(mt).
__global__ __launch_bounds__(1024, 4) void k_fused(
    const _Float16* __restrict__ A2F,  // frag-major spike matrix (2.62 MB, L2-resident)
    const float* __restrict__ W2,      // [32000][512] fp32
    const float* __restrict__ b2,
    const float* __restrict__ pa2, const float* __restrict__ pb2,
    float* __restrict__ out) {
  __shared__ float Cl[2][2][64 * 132];  // [buf][kq plane] = 132 KB total

  const int tid  = threadIdx.x;
  const int lane = tid & 63;
  const int wid  = tid >> 6;           // 0..15
  const int kq   = wid >> 3;           // K half: k-chunks kq*8 .. kq*8+7 (of 32-wide)
  const int wm   = (wid >> 2) & 1;     // m half (rows wm*32..+31)
  const int wn   = wid & 3;            // n quarter (cols wn*32..+31 of 128)
  const int n0   = blockIdx.x * 128;

  const int lr  = lane & 15;
  const int lk8 = (lane >> 4) * 8;
  const int cr  = (lane >> 4) * 4, cc = lane & 15;

  // ---- B prologue: 2 n-frags x 8 k-frags, fp16 (k-chunks kq*8+KF) ----
  f16x8 bfr[2][8];
#pragma unroll
  for (int ni = 0; ni < 2; ++ni) {
    const int n = n0 + wn * 32 + ni * 16 + lr;
    const float* wp = W2 + (size_t)n * NH + kq * 256;
#pragma unroll
    for (int kf = 0; kf < 8; ++kf) {
      const float4 wa = *(const float4*)(wp + kf * 32 + lk8);
      const float4 wb = *(const float4*)(wp + kf * 32 + lk8 + 4);
      f16x8 v;
      v[0] = (_Float16)wa.x; v[1] = (_Float16)wa.y;
      v[2] = (_Float16)wa.z; v[3] = (_Float16)wa.w;
      v[4] = (_Float16)wb.x; v[5] = (_Float16)wb.y;
      v[6] = (_Float16)wb.z; v[7] = (_Float16)wb.w;
      bfr[ni][kf] = v;
    }
  }

  const float a2  = clip01(pa2[0]);
  const float bcl = clip01(pb2[0]);
  const int vv = tid & 127;            // recurrence: owned column
  const int bb = tid >> 7;             // recurrence: owned batch
  const float b2v = b2[n0 + vv];
  float syn = 0.f, mem = 0.f;
  unsigned spkmask = 0;
  f32x4 acc[2][2] = {};

  // wave-constant A base: frag (MT,P,mb) at pAW + MT*32768 + P*2048 + mb*512;
  // intra-frag per-lane offset = (lane&15)*32 + (lane>>4)*8  (row-major [lr][khi][e])
  const _Float16* pAW = A2F + (size_t)kq * 16384 + wm * 1024 + lr * 32 + lk8;

  f16x8 x0, x1, x2, x3, y0, y1, y2, y3;

#define LOADC(MT, P, S0, S1, S2, S3)                                          \
  {                                                                           \
    const _Float16* fb = pAW + (size_t)(MT) * 32768 + (P) * 4096;             \
    S0 = *(const f16x8*)(fb);          /* kf(2P)   mb0 */                     \
    S1 = *(const f16x8*)(fb + 512);    /* kf(2P)   mb1 */                     \
    S2 = *(const f16x8*)(fb + 2048);   /* kf(2P+1) mb0 */                     \
    S3 = *(const f16x8*)(fb + 2560);   /* kf(2P+1) mb1 */                     \
  }

#define MFMAC(P, S0, S1, S2, S3)                                              \
  {                                                                           \
    acc[0][0] = __builtin_amdgcn_mfma_f32_16x16x32_f16(S0, bfr[0][(P)*2], acc[0][0], 0, 0, 0); \
    acc[1][0] = __builtin_amdgcn_mfma_f32_16x16x32_f16(S1, bfr[0][(P)*2], acc[1][0], 0, 0, 0); \
    acc[0][1] = __builtin_amdgcn_mfma_f32_16x16x32_f16(S0, bfr[1][(P)*2], acc[0][1], 0, 0, 0); \
    acc[1][1] = __builtin_amdgcn_mfma_f32_16x16x32_f16(S1, bfr[1][(P)*2], acc[1][1], 0, 0, 0); \
    acc[0][0] = __builtin_amdgcn_mfma_f32_16x16x32_f16(S2, bfr[0][(P)*2+1], acc[0][0], 0, 0, 0); \
    acc[1][0] = __builtin_amdgcn_mfma_f32_16x16x32_f16(S3, bfr[0][(P)*2+1], acc[1][0], 0, 0, 0); \
    acc[0][1] = __builtin_amdgcn_mfma_f32_16x16x32_f16(S2, bfr[1][(P)*2+1], acc[0][1], 0, 0, 0); \
    acc[1][1] = __builtin_amdgcn_mfma_f32_16x16x32_f16(S3, bfr[1][(P)*2+1], acc[1][1], 0, 0, 0); \
  }

  // recurrence for tile mtq: 16 hoisted ds_reads (static idx) then the serial chain
  auto recur = [&](int mtq) {
    const float* C0 = Cl[mtq & 1][0];
    const float* C1 = Cl[mtq & 1][1];
    float v0[8], v1[8];
#pragma unroll
    for (int st = 0; st < 8; ++st) {
      const int idx = (st * 8 + bb) * 132 + vv;
      v0[st] = C0[idx];
      v1[st] = C1[idx];
    }
#pragma unroll
    for (int st = 0; st < 8; ++st) {
      const int gs = mtq * 8 + st;
      float cur2 = __fadd_rn(__fadd_rn(v0[st], v1[st]), b2v);
      float rst = (mem > TH2) ? 1.f : 0.f;             // reset from OLD mem2
      syn = __fadd_rn(__fmul_rn(a2, syn), cur2);
      mem = __fsub_rn(__fadd_rn(__fmul_rn(bcl, mem), syn), rst);
      if (gs % 20 == 19)                               // last inner step of seq pos
        spkmask |= (mem > TH2 ? 1u : 0u) << (gs / 20);
    }
  };

  LOADC(0, 0, x0, x1, x2, x3);

  for (int mt = 0; mt < 40; ++mt) {
    LOADC(mt, 1, y0, y1, y2, y3);
    if (mt > 0) recur(mt - 1);         // overlaps the MFMA cluster below
    __builtin_amdgcn_s_setprio(1);
    MFMAC(0, x0, x1, x2, x3);
    LOADC(mt, 2, x0, x1, x2, x3);  MFMAC(1, y0, y1, y2, y3);
    LOADC(mt, 3, y0, y1, y2, y3);  MFMAC(2, x0, x1, x2, x3);
    if (mt < 39) LOADC(mt + 1, 0, x0, x1, x2, x3);
    MFMAC(3, y0, y1, y2, y3);
    __builtin_amdgcn_s_setprio(0);

    // ---- epilogue: each wave writes its kq plane quadrant of Cl[mt&1] ----
    float* Cw = Cl[mt & 1][kq];
#pragma unroll
    for (int mi = 0; mi < 2; ++mi)
#pragma unroll
      for (int ni = 0; ni < 2; ++ni) {
#pragma unroll
        for (int j = 0; j < 4; ++j)
          Cw[(wm * 32 + mi * 16 + cr + j) * 132 + wn * 32 + ni * 16 + cc] = acc[mi][ni][j];
        acc[mi][ni] = (f32x4){0.f, 0.f, 0.f, 0.f};
      }
    bar_lds();                         // ONE rendezvous per mt
  }
  recur(39);
#undef LOADC
#undef MFMAC

  // ---- outputs ----
#pragma unroll
  for (int s = 0; s < NS; ++s)
    out[((size_t)bb * NS + s) * NV + n0 + vv] = (spkmask >> s) & 1 ? 1.f : 0.f;
  out[(size_t)4100096 + (size_t)bb * NV + n0 + vv] = syn;   // syn2
  out[(size_t)4356096 + (size_t)bb * NV + n0 + vv] = mem;   // mem2
}

extern "C" void kernel_launch(void* const* d_in, const int* in_sizes, int n_in,
                              void* d_out, int out_size, void* d_ws, size_t ws_size,
                              hipStream_t stream) {
  const int*   x     = (const int*)d_in[0];
  const float* embed = (const float*)d_in[1];
  const float* W1    = (const float*)d_in[2];
  const float* b1    = (const float*)d_in[3];
  const float* W2    = (const float*)d_in[4];
  const float* b2    = (const float*)d_in[5];
  const float* pb1   = (const float*)d_in[6];
  const float* pa2   = (const float*)d_in[7];
  const float* pb2   = (const float*)d_in[8];
  float* out = (float*)d_out;

  _Float16* A2F = (_Float16*)d_ws;                     // 40*16*4*512 f16 = 2.62 MB

  hipLaunchKernelGGL(k_front, dim3(16), dim3(256), 0, stream,
                     x, embed, W1, b1, pb1, A2F, out + 4096000);
  hipLaunchKernelGGL(k_fused, dim3(NV / 128), dim3(1024), 0, stream,
                     A2F, W2, b2, pa2, pb2, out);
}

// Round 17
// 142.568 us; speedup vs baseline: 1.5025x; 1.5025x over previous
//
#include <hip/hip_runtime.h>
#include <cstdint>

constexpr int NV = 32000;   // vocab / N
constexpr int NE = 256;     // embed dim
constexpr int NH = 512;     // hidden / K
constexpr int NB = 8;       // batch
constexpr int NS = 16;      // seq len
constexpr int NT = 20;      // time steps
constexpr float TH1 = 0.8f;
constexpr float TH2 = 1.0f;

typedef _Float16 f16x8 __attribute__((ext_vector_type(8)));
typedef float f32x4 __attribute__((ext_vector_type(4)));

__device__ inline float clip01(float v) { return fminf(fmaxf(v, 0.f), 1.f); }

#define GL_LDS(gp, lp) \
  __builtin_amdgcn_global_load_lds((const __attribute__((address_space(1))) void*)(gp), \
                                   (__attribute__((address_space(3))) void*)(lp), 16, 0, 0)

__device__ inline void barsched() {
  __builtin_amdgcn_s_barrier();
  __builtin_amdgcn_sched_barrier(0);
}

// ---------------- K1: cur1[b][s][h] = embed[x[b,s],:] . W1[h,:] + b1[h] ----------------
__global__ void k_cur1(const int* __restrict__ x, const float* __restrict__ embed,
                       const float* __restrict__ W1, const float* __restrict__ b1,
                       float* __restrict__ cur1) {
  __shared__ float e[NE];
  int bs = blockIdx.x;
  int row = x[bs];
  e[threadIdx.x] = embed[(size_t)row * NE + threadIdx.x];
  __syncthreads();
  for (int hh = 0; hh < 2; ++hh) {
    int h = threadIdx.x + hh * 256;
    const float* w = W1 + (size_t)h * NE;
    float acc = 0.f;
#pragma unroll 8
    for (int k = 0; k < NE; ++k) acc = fmaf(e[k], w[k], acc);
    cur1[(size_t)bs * NH + h] = acc + b1[h];
  }
}

// ---------------- K2: leaky recurrence -> packed spike tiles (K=512, spikes only) ---------
// A2P = 320 tiles of [64 rows][64 cols] f16 (8KB), tile u = (m>>6)*8 + (h>>6),
// elem (row=m&63, col=h&63) stored at row*64 + (col ^ ((row&7)*8)).  row&7 == b.
// Stores from 64 consecutive h = one 128B dense run (xor is a permutation within the run).
// Grid 64 x 64: one chain per thread, spread over 64 CUs (4x more than 16x256).
__global__ void k_spk1(const float* __restrict__ cur1, const float* __restrict__ pbeta1,
                       _Float16* __restrict__ A2P, float* __restrict__ mem1_out) {
  int g = blockIdx.x * blockDim.x + threadIdx.x;   // 4096 = NB*NH
  int b = g >> 9, h = g & 511;
  float bc = clip01(pbeta1[0]);
  float mem = 0.f;
  const _Float16 one  = (_Float16)1.0f;
  const _Float16 zero = (_Float16)0.0f;
  const int ks  = h >> 6;
  const int col = (h & 63) ^ (b << 3);
  for (int s = 0; s < NS; ++s) {
    float c = cur1[((size_t)b * NS + s) * NH + h];
    for (int t = 0; t < NT; ++t) {
      float rst = (mem > TH1) ? TH1 : 0.f;
      mem = __fsub_rn(__fadd_rn(__fmul_rn(bc, mem), c), rst);    // np order
      bool spk = mem > TH1;
      int gs = s * NT + t;
      size_t addr = ((size_t)((gs >> 3) * 8 + ks)) * 4096 + ((gs & 7) * 8 + b) * 64 + col;
      A2P[addr] = spk ? one : zero;
    }
  }
  mem1_out[g] = mem;
}

// ---------------- Fused: fp16 B-in-registers GEMM (n=128 strip) + synaptic recurrence -----
// Grid 250 = 1 block/CU.  Block = 1024 thr = 16 waves: (kh 2) x (wm 2) x (wn 4).
// Each wave: B slice (n=32, contiguous K-half of 256, fp16) = 16 f16x8 frags = 64 regs.
// A streamed via global_load_lds: ONE 64KB full-K group per mt, ring-2 (128 KB LDS),
// prefetch = full mt.  C tile aliases the just-consumed LDS slot ([row][col][2] f32).
__global__ __launch_bounds__(1024, 4) void k_fused(
    const _Float16* __restrict__ A2P,  // 320 x 8KB packed spike tiles
    const float* __restrict__ W2,      // [32000][512] fp32
    const float* __restrict__ b2,
    const float* __restrict__ pa2, const float* __restrict__ pb2,
    float* __restrict__ out) {
  __shared__ __attribute__((aligned(16))) _Float16 As[2 * 32768];  // 128 KB (2 x full-K group)

  const int tid  = threadIdx.x;
  const int lane = tid & 63;
  const int wid  = tid >> 6;           // 0..15
  const int kh   = wid >> 3;           // K half: chunks kh*4 .. kh*4+3
  const int wm   = (wid >> 2) & 1;     // m half (rows wm*32..+31)
  const int wn   = wid & 3;            // n quarter (cols wn*32..+31 of 128)
  const int n0   = blockIdx.x * 128;

  const int lr  = lane & 15;
  const int lk8 = (lane >> 4) * 8;
  const int sw  = (lr & 7) * 8;        // read-side swizzle
  const int cr  = (lane >> 4) * 4, cc = lane & 15;

  // ---- B prologue: 2 n-frags x 8 k-frags, fp16 (k-chunks kh*4+p, p=0..3) ----
  f16x8 bfr[2][8];
#pragma unroll
  for (int ni = 0; ni < 2; ++ni) {
    const int n = n0 + wn * 32 + ni * 16 + lr;
    const float* wp = W2 + (size_t)n * NH;
#pragma unroll
    for (int p = 0; p < 4; ++p) {
#pragma unroll
      for (int kf = 0; kf < 2; ++kf) {
        const int k0 = (kh * 4 + p) * 64 + kf * 32 + lk8;
        const float4 wa = *(const float4*)(wp + k0);
        const float4 wb = *(const float4*)(wp + k0 + 4);
        f16x8 v;
        v[0] = (_Float16)wa.x; v[1] = (_Float16)wa.y;
        v[2] = (_Float16)wa.z; v[3] = (_Float16)wa.w;
        v[4] = (_Float16)wb.x; v[5] = (_Float16)wb.y;
        v[6] = (_Float16)wb.z; v[7] = (_Float16)wb.w;
        bfr[ni][p * 2 + kf] = v;
      }
    }
  }

  const float a2  = clip01(pa2[0]);
  const float bcl = clip01(pb2[0]);
  const int vv = tid & 127;            // recurrence: owned column
  const int bb = tid >> 7;             // recurrence: owned batch
  const float b2v = b2[n0 + vv];
  float syn = 0.f, mem = 0.f;
  unsigned spkmask = 0;
  f32x4 acc[2][2] = {};

  // ---- staging: full-K group (8 tiles = 64KB) per mt; 4 GL_LDS per wave ----
  const _Float16* pA = A2P + wid * 512 + lane * 8;
  _Float16* dA = As + wid * 512;
  auto stage = [&](int g) {
    const _Float16* s = pA + (size_t)g * 32768;
    _Float16* d = dA + (g & 1) * 32768;
    GL_LDS(s,         d);
    GL_LDS(s + 8192,  d + 8192);
    GL_LDS(s + 16384, d + 16384);
    GL_LDS(s + 24576, d + 24576);
  };

  asm volatile("s_waitcnt vmcnt(0)" ::: "memory");   // B loads retired: clean FIFO
  barsched();
  stage(0);

#define CHUNK(C)                                                                 \
  {                                                                              \
    const int tb = sb + (kh * 4 + (C)) * 4096;                                   \
    {                                                                            \
      const int col = lk8 ^ sw;                                                  \
      const f16x8 a0 = *(const f16x8*)&As[tb + (wm * 32 + lr) * 64 + col];       \
      const f16x8 a1 = *(const f16x8*)&As[tb + (wm * 32 + 16 + lr) * 64 + col];  \
      acc[0][0] = __builtin_amdgcn_mfma_f32_16x16x32_f16(a0, bfr[0][(C)*2], acc[0][0], 0, 0, 0); \
      acc[1][0] = __builtin_amdgcn_mfma_f32_16x16x32_f16(a1, bfr[0][(C)*2], acc[1][0], 0, 0, 0); \
      acc[0][1] = __builtin_amdgcn_mfma_f32_16x16x32_f16(a0, bfr[1][(C)*2], acc[0][1], 0, 0, 0); \
      acc[1][1] = __builtin_amdgcn_mfma_f32_16x16x32_f16(a1, bfr[1][(C)*2], acc[1][1], 0, 0, 0); \
    }                                                                            \
    {                                                                            \
      const int col = (32 + lk8) ^ sw;                                           \
      const f16x8 a0 = *(const f16x8*)&As[tb + (wm * 32 + lr) * 64 + col];       \
      const f16x8 a1 = *(const f16x8*)&As[tb + (wm * 32 + 16 + lr) * 64 + col];  \
      acc[0][0] = __builtin_amdgcn_mfma_f32_16x16x32_f16(a0, bfr[0][(C)*2+1], acc[0][0], 0, 0, 0); \
      acc[1][0] = __builtin_amdgcn_mfma_f32_16x16x32_f16(a1, bfr[0][(C)*2+1], acc[1][0], 0, 0, 0); \
      acc[0][1] = __builtin_amdgcn_mfma_f32_16x16x32_f16(a0, bfr[1][(C)*2+1], acc[0][1], 0, 0, 0); \
      acc[1][1] = __builtin_amdgcn_mfma_f32_16x16x32_f16(a1, bfr[1][(C)*2+1], acc[1][1], 0, 0, 0); \
    }                                                                            \
  }

  for (int mt = 0; mt < 40; ++mt) {
    asm volatile("s_waitcnt vmcnt(0)" ::: "memory");   // group mt resident
    barsched();
    if (mt < 39) stage(mt + 1);                        // full-mt lookahead into other slot
    const int sb = (mt & 1) * 32768;
    CHUNK(0) CHUNK(1) CHUNK(2) CHUNK(3)
    barsched();                                        // all A-reads of slot done -> slot reusable
    // ---- C tile aliases the consumed slot: [64 rows][128 cols][2 planes] f32 = 64 KB ----
    float* Cl = (float*)&As[sb];
#pragma unroll
    for (int mi = 0; mi < 2; ++mi)
#pragma unroll
      for (int ni = 0; ni < 2; ++ni) {
#pragma unroll
        for (int j = 0; j < 4; ++j)
          Cl[((wm * 32 + mi * 16 + cr + j) * 128 + wn * 32 + ni * 16 + cc) * 2 + kh] = acc[mi][ni][j];
        acc[mi][ni] = (f32x4){0.f, 0.f, 0.f, 0.f};
      }
    barsched();                                        // both kh planes visible
    // ---- 8 recurrence steps: all 1024 threads (b=tid>>7, v=tid&127) ----
#pragma unroll
    for (int st = 0; st < 8; ++st) {
      const int gs = mt * 8 + st;
      const float2 c2 = *(const float2*)&Cl[((st * 8 + bb) * 128 + vv) * 2];
      float cur2 = __fadd_rn(__fadd_rn(c2.x, c2.y), b2v);
      float rst = (mem > TH2) ? 1.f : 0.f;             // reset from OLD mem2
      syn = __fadd_rn(__fmul_rn(a2, syn), cur2);
      mem = __fsub_rn(__fadd_rn(__fmul_rn(bcl, mem), syn), rst);
      if (gs % 20 == 19)                               // last inner step of seq pos
        spkmask |= (mem > TH2 ? 1u : 0u) << (gs / 20);
    }
    // next mt's top barrier orders these Cl reads before the next stage/epilogue writes
  }
#undef CHUNK

  // ---- outputs (outside the loop; vmcnt FIFO was kept pure) ----
#pragma unroll
  for (int s = 0; s < NS; ++s)
    out[((size_t)bb * NS + s) * NV + n0 + vv] = (spkmask >> s) & 1 ? 1.f : 0.f;
  out[(size_t)4100096 + (size_t)bb * NV + n0 + vv] = syn;   // syn2
  out[(size_t)4356096 + (size_t)bb * NV + n0 + vv] = mem;   // mem2
}

extern "C" void kernel_launch(void* const* d_in, const int* in_sizes, int n_in,
                              void* d_out, int out_size, void* d_ws, size_t ws_size,
                              hipStream_t stream) {
  const int*   x     = (const int*)d_in[0];
  const float* embed = (const float*)d_in[1];
  const float* W1    = (const float*)d_in[2];
  const float* b1    = (const float*)d_in[3];
  const float* W2    = (const float*)d_in[4];
  const float* b2    = (const float*)d_in[5];
  const float* pb1   = (const float*)d_in[6];
  const float* pa2   = (const float*)d_in[7];
  const float* pb2   = (const float*)d_in[8];
  float* out = (float*)d_out;

  char* ws = (char*)d_ws;
  float* cur1 = (float*)ws;                            // 262144 B
  _Float16* A2P = (_Float16*)(ws + 262144);            // 320 tiles x 8KB = 2.62 MB

  hipLaunchKernelGGL(k_cur1, dim3(NB * NS), dim3(256), 0, stream, x, embed, W1, b1, cur1);
  hipLaunchKernelGGL(k_spk1, dim3(64), dim3(64), 0, stream, cur1, pb1, A2P, out + 4096000);
  hipLaunchKernelGGL(k_fused, dim3(NV / 128), dim3(1024), 0, stream,
                     A2P, W2, b2, pa2, pb2, out);
}